// Round 3
// baseline (347.589 us; speedup 1.0000x reference)
//
#include <hip/hip_runtime.h>

// Problem constants (from reference)
#define B_ 2048
#define S_ 200
#define D_ 128
#define H_ 64
#define MASK_SCALE 1e10f

typedef __attribute__((ext_vector_type(8))) short short8_t;            // 8 bf16 in 4 VGPRs
typedef __attribute__((ext_vector_type(4))) float f32x4;
typedef __attribute__((ext_vector_type(4))) unsigned short ushort4_t;  // 8B

__device__ __forceinline__ unsigned short f2bf(float f) {
    unsigned u = __float_as_uint(f);
    unsigned r = (u + 0x7fffu + ((u >> 16) & 1u)) >> 16;   // round-to-nearest-even
    return (unsigned short)r;
}
__device__ __forceinline__ float bf2f(unsigned short v) {
    return __uint_as_float(((unsigned)v) << 16);
}

// ---------------------------------------------------------------------------
// prep: build Wh (=W1+W2) in bf16, pre-swizzled to MFMA B-fragment order.
// W is [3D,H] row-major; 16x16x32 B-frag: n = nt*16+(lane&15),
// k = kt*32+(lane>>4)*8+j; stored so each lane loads 16 contiguous bytes.
// ---------------------------------------------------------------------------
__global__ __launch_bounds__(256) void prep_w(const float* __restrict__ W,
                                              unsigned short* __restrict__ wfrag) {
    int idx = blockIdx.x * 256 + threadIdx.x;     // 0..8191
    int d = idx >> 6;          // 0..127
    int h = idx & 63;          // 0..63
    float w1 = W[d * H_ + h];
    float w2 = W[(D_ + d) * H_ + h];
    int kt = d >> 5, q = (d >> 3) & 3, j = d & 7;
    int nt = h >> 4, lm = h & 15;
    int lane = (q << 4) | lm;
    wfrag[((kt * 4 + nt) * 64 + lane) * 8 + j] = f2bf(w1 + w2);
}

// ---------------------------------------------------------------------------
// Fused: one block per batch, 3 blocks/CU.
//   waves 0-2: stage his[b] -> LDS bf16 (coalesced float4)
//   wave 3   : tproj[h] = W_bias[h] + sum_d tgt[d]*(W3-W2)[d][h]  (inline)
//   then: MFMA alpha -> softmax -> LDS pool -> out
// ---------------------------------------------------------------------------
__global__ __launch_bounds__(256, 3) void fused_kernel(const float* __restrict__ his,
                                                       const float* __restrict__ target,
                                                       const float* __restrict__ mask,
                                                       const float* __restrict__ W,
                                                       const float* __restrict__ W_bias,
                                                       const float* __restrict__ Ovec,
                                                       const unsigned short* __restrict__ wfrag,
                                                       float* __restrict__ out) {
    __shared__ unsigned short hisb[S_ * D_];        // 51,200 B (stride 128, no pad)
    __shared__ float alpha_s[208];                  // 13 tiles x 16 rows
    __shared__ float red8[8];
    __shared__ float tp_s[H_];
    __shared__ float ov_s[H_];
    __shared__ float pool_s[3 * D_];                // partials from waves 1..3

    const int b    = blockIdx.x;
    const int t    = threadIdx.x;
    const int lane = t & 63;
    const int wv   = t >> 6;
    const int lm   = lane & 15;
    const int q    = lane >> 4;

    // mask load in flight during staging
    float mk = (t < S_) ? mask[(size_t)b * S_ + t] : 0.f;

    // B fragments: 16 x 16B per lane (L2-resident, same for all blocks)
    short8_t bfrag[16];
    #pragma unroll
    for (int f = 0; f < 16; ++f)
        bfrag[f] = *(const short8_t*)(wfrag + ((size_t)(f * 64 + lane)) * 8);

    if (wv < 3) {
        // ---- stage his[b] -> LDS bf16; 192 threads, fully coalesced ----
        const float4* hb4 = (const float4*)(his + (size_t)b * S_ * D_);
        const int tid3 = wv * 64 + lane;
        for (int i = tid3; i < S_ * D_ / 4; i += 192) {
            float4 x = hb4[i];
            ushort4_t v;
            v[0] = f2bf(x.x); v[1] = f2bf(x.y); v[2] = f2bf(x.z); v[3] = f2bf(x.w);
            *(ushort4_t*)(&hisb[i * 4]) = v;
        }
    } else {
        // ---- wave 3: inline tproj + Ovec ----
        const float* tg = target + (size_t)b * D_;
        float acc = W_bias[lane];
        #pragma unroll 4
        for (int d = 0; d < D_; ++d) {
            float w2 = W[(D_ + d) * H_ + lane];
            float w3 = W[(2 * D_ + d) * H_ + lane];
            acc = fmaf(tg[d], w3 - w2, acc);
        }
        tp_s[lane] = acc;
        ov_s[lane] = Ovec[lane];
    }
    __syncthreads();

    // ---- alpha via MFMA: 13 tiles of 16 rows over 4 waves ----
    for (int tile = wv; tile < 13; tile += 4) {
        int row0 = tile * 16;
        int ar = row0 + lm; if (ar > S_ - 1) ar = S_ - 1;   // clamp pad rows
        const unsigned short* ap = &hisb[ar * D_ + q * 8];

        f32x4 acc[4];
        #pragma unroll
        for (int nt = 0; nt < 4; ++nt) acc[nt] = (f32x4){0.f, 0.f, 0.f, 0.f};

        #pragma unroll
        for (int kt = 0; kt < 4; ++kt) {
            short8_t a = *(const short8_t*)(ap + kt * 32);
            #pragma unroll
            for (int nt = 0; nt < 4; ++nt)
                acc[nt] = __builtin_amdgcn_mfma_f32_16x16x32_bf16(a, bfrag[kt * 4 + nt], acc[nt], 0, 0, 0);
        }

        // epilogue: +tproj, relu, dot O (O_bias softmax-invariant -> skipped)
        float part[4];
        #pragma unroll
        for (int r = 0; r < 4; ++r) {
            float sum = 0.f;
            #pragma unroll
            for (int nt = 0; nt < 4; ++nt) {
                int h = nt * 16 + lm;
                float v = acc[nt][r] + tp_s[h];
                v = fmaxf(v, 0.f);
                sum = fmaf(v, ov_s[h], sum);
            }
            part[r] = sum;
        }
        #pragma unroll
        for (int off = 1; off < 16; off <<= 1) {
            #pragma unroll
            for (int r = 0; r < 4; ++r)
                part[r] += __shfl_xor(part[r], off);
        }
        if (lm == 0) {
            #pragma unroll
            for (int r = 0; r < 4; ++r)
                alpha_s[row0 + q * 4 + r] = part[r];
        }
    }
    __syncthreads();

    // ---- block softmax over s = 0..199 ----
    float a = (t < S_) ? alpha_s[t] - mk * MASK_SCALE : -INFINITY;
    float m = a;
    #pragma unroll
    for (int off = 1; off < 64; off <<= 1) m = fmaxf(m, __shfl_xor(m, off));
    if (lane == 0) red8[wv] = m;
    __syncthreads();
    m = fmaxf(fmaxf(red8[0], red8[1]), fmaxf(red8[2], red8[3]));
    float e = (t < S_) ? __expf(a - m) : 0.f;
    float ssum = e;
    #pragma unroll
    for (int off = 1; off < 64; off <<= 1) ssum += __shfl_xor(ssum, off);
    if (lane == 0) red8[4 + wv] = ssum;
    __syncthreads();
    float inv = 1.f / (red8[4] + red8[5] + red8[6] + red8[7]);
    __syncthreads();                 // alpha_s reads done before overwrite below
    if (t < S_) alpha_s[t] = e * inv;
    __syncthreads();

    // ---- pooling: out[b][d] = sum_s w[s] * his_bf[s][d] ----
    const int d4 = t & 31;           // ushort4 index: covers d = d4*4 .. d4*4+3
    const int sg = t >> 5;           // 0..7 s-groups (lane<32 -> sg=2wv, else 2wv+1)
    float acc0 = 0.f, acc1 = 0.f, acc2 = 0.f, acc3 = 0.f;
    for (int s = sg; s < S_; s += 8) {
        float w = alpha_s[s];        // wave-half-uniform broadcast
        ushort4_t v = *(const ushort4_t*)(&hisb[s * D_ + d4 * 4]);
        acc0 = fmaf(w, bf2f(v[0]), acc0);
        acc1 = fmaf(w, bf2f(v[1]), acc1);
        acc2 = fmaf(w, bf2f(v[2]), acc2);
        acc3 = fmaf(w, bf2f(v[3]), acc3);
    }
    // combine the two s-groups within each wave
    acc0 += __shfl_xor(acc0, 32);
    acc1 += __shfl_xor(acc1, 32);
    acc2 += __shfl_xor(acc2, 32);
    acc3 += __shfl_xor(acc3, 32);
    if (wv && lane < 32) {
        float4 p; p.x = acc0; p.y = acc1; p.z = acc2; p.w = acc3;
        *(float4*)(&pool_s[(wv - 1) * D_ + d4 * 4]) = p;
    }
    __syncthreads();
    if (wv == 0 && lane < 32) {
        #pragma unroll
        for (int k = 0; k < 3; ++k) {
            const float4 p = *(const float4*)(&pool_s[k * D_ + d4 * 4]);
            acc0 += p.x; acc1 += p.y; acc2 += p.z; acc3 += p.w;
        }
        float4 o; o.x = acc0; o.y = acc1; o.z = acc2; o.w = acc3;
        *(float4*)(out + (size_t)b * D_ + d4 * 4) = o;
    }
}

// ---------------------------------------------------------------------------
extern "C" void kernel_launch(void* const* d_in, const int* in_sizes, int n_in,
                              void* d_out, int out_size, void* d_ws, size_t ws_size,
                              hipStream_t stream) {
    const float* his    = (const float*)d_in[0];
    const float* target = (const float*)d_in[1];
    const float* mask   = (const float*)d_in[2];
    const float* W      = (const float*)d_in[3];
    const float* W_bias = (const float*)d_in[4];
    const float* Ovec   = (const float*)d_in[5];
    // O_bias (d_in[6]) is softmax-invariant -> unused
    float* out = (float*)d_out;

    unsigned short* wfrag = (unsigned short*)d_ws;   // 8192 us (16 KB)

    prep_w<<<32, 256, 0, stream>>>(W, wfrag);
    fused_kernel<<<B_, 256, 0, stream>>>(his, target, mask, W, W_bias, Ovec, wfrag, out);
}

// Round 4
// 320.107 us; speedup vs baseline: 1.0859x; 1.0859x over previous
//
#include <hip/hip_runtime.h>

// Problem constants (from reference)
#define B_ 2048
#define S_ 200
#define D_ 128
#define H_ 64
#define MASK_SCALE 1e10f

typedef __attribute__((ext_vector_type(8))) short short8_t;            // 8 bf16 in 4 VGPRs
typedef __attribute__((ext_vector_type(4))) float f32x4;
typedef __attribute__((ext_vector_type(4))) unsigned short ushort4_t;  // 8B

__device__ __forceinline__ unsigned short f2bf(float f) {
    unsigned u = __float_as_uint(f);
    unsigned r = (u + 0x7fffu + ((u >> 16) & 1u)) >> 16;   // round-to-nearest-even
    return (unsigned short)r;
}
__device__ __forceinline__ float bf2f(unsigned short v) {
    return __uint_as_float(((unsigned)v) << 16);
}

// ---------------------------------------------------------------------------
// prep: blocks 0..31  -> wfrag: Wh(=W1+W2) bf16, MFMA B-fragment order
//       blocks 32..543-> tproj[b][h] = W_bias[h] + sum_d tgt[d]*(W3-W2)[d][h]
// ---------------------------------------------------------------------------
__global__ __launch_bounds__(256) void prep(const float* __restrict__ W,
                                            const float* __restrict__ W_bias,
                                            const float* __restrict__ target,
                                            unsigned short* __restrict__ wfrag,
                                            float* __restrict__ tproj) {
    const int blk = blockIdx.x;
    const int t = threadIdx.x;
    if (blk < 32) {
        int idx = blk * 256 + t;   // 0..8191
        int d = idx >> 6;          // 0..127
        int h = idx & 63;          // 0..63
        float w1 = W[d * H_ + h];
        float w2 = W[(D_ + d) * H_ + h];
        int kt = d >> 5, q = (d >> 3) & 3, j = d & 7;
        int nt = h >> 4, lm = h & 15;
        int lane = (q << 4) | lm;
        wfrag[((kt * 4 + nt) * 64 + lane) * 8 + j] = f2bf(w1 + w2);
    } else {
        int lane = t & 63, wv = t >> 6;
        int bb = (blk - 32) * 4 + wv;              // 0..2047
        const float* tg = target + (size_t)bb * D_;
        float acc = W_bias[lane];
        #pragma unroll 4
        for (int d = 0; d < D_; ++d) {
            float w2 = W[(D_ + d) * H_ + lane];
            float w3 = W[(2 * D_ + d) * H_ + lane];
            acc = fmaf(tg[d], w3 - w2, acc);
        }
        tproj[bb * H_ + lane] = acc;
    }
}

// ---------------------------------------------------------------------------
// Fused: one block per batch, 3 blocks/CU (51.2 KB his tile, XOR-swizzled).
// Stage his[b] -> LDS bf16 (batched float4, all 4 waves), MFMA alpha,
// block softmax, weighted pool from LDS.
// LDS layout: row s = 256 B = 16 chunks of 16 B; chunk c stored at c^(s&15).
// ---------------------------------------------------------------------------
__global__ __launch_bounds__(256, 3) void fused_kernel(const float* __restrict__ his,
                                                       const float* __restrict__ mask,
                                                       const unsigned short* __restrict__ wfrag,
                                                       const float* __restrict__ tproj,
                                                       const float* __restrict__ Ovec,
                                                       float* __restrict__ out) {
    __shared__ unsigned short hisb[S_ * D_];        // 51,200 B, swizzled
    __shared__ float alpha_s[208];                  // 13 tiles x 16 rows
    __shared__ float red8[8];
    __shared__ float tp_s[H_];
    __shared__ float ov_s[H_];
    __shared__ float pool_s[3 * D_];

    const int b    = blockIdx.x;
    const int t    = threadIdx.x;
    const int lane = t & 63;
    const int wv   = t >> 6;
    const int lm   = lane & 15;
    const int q    = lane >> 4;

    // small loads in flight early
    float mk = (t < S_) ? mask[(size_t)b * S_ + t] : 0.f;
    if (t < H_) {
        tp_s[t] = tproj[b * H_ + t];
        ov_s[t] = Ovec[t];
    }

    // B fragments: 16 x 16B per lane (L2-resident, same for all blocks)
    short8_t bfrag[16];
    #pragma unroll
    for (int f = 0; f < 16; ++f)
        bfrag[f] = *(const short8_t*)(wfrag + ((size_t)(f * 64 + lane)) * 8);

    // ---- stage his[b] -> LDS bf16: 25 float4/thread, 5 batches of 5 ----
    const float4* hb4 = (const float4*)(his + (size_t)b * S_ * D_);
    #pragma unroll
    for (int g = 0; g < 5; ++g) {
        float4 x[5];
        #pragma unroll
        for (int j = 0; j < 5; ++j)
            x[j] = hb4[t + (g * 5 + j) * 256];
        #pragma unroll
        for (int j = 0; j < 5; ++j) {
            int i  = t + (g * 5 + j) * 256;
            int s  = i >> 5;                 // row
            int d8 = i & 31;                 // 8B index in row
            int pc = (d8 >> 1) ^ (s & 15);   // swizzled 16B chunk
            ushort4_t v;
            v[0] = f2bf(x[j].x); v[1] = f2bf(x[j].y);
            v[2] = f2bf(x[j].z); v[3] = f2bf(x[j].w);
            *(ushort4_t*)((char*)hisb + s * 256 + pc * 16 + (d8 & 1) * 8) = v;
        }
    }
    __syncthreads();

    // ---- alpha via MFMA: 13 tiles of 16 rows over 4 waves ----
    for (int tile = wv; tile < 13; tile += 4) {
        int row0 = tile * 16;
        int ar = row0 + lm; if (ar > S_ - 1) ar = S_ - 1;   // clamp pad rows

        f32x4 acc[4];
        #pragma unroll
        for (int nt = 0; nt < 4; ++nt) acc[nt] = (f32x4){0.f, 0.f, 0.f, 0.f};

        #pragma unroll
        for (int kt = 0; kt < 4; ++kt) {
            int c = (kt * 4 + q) ^ (ar & 15);
            short8_t a = *(const short8_t*)((const char*)hisb + ar * 256 + c * 16);
            #pragma unroll
            for (int nt = 0; nt < 4; ++nt)
                acc[nt] = __builtin_amdgcn_mfma_f32_16x16x32_bf16(a, bfrag[kt * 4 + nt], acc[nt], 0, 0, 0);
        }

        // epilogue: +tproj, relu, dot O (O_bias softmax-invariant -> skipped)
        float part[4];
        #pragma unroll
        for (int r = 0; r < 4; ++r) {
            float sum = 0.f;
            #pragma unroll
            for (int nt = 0; nt < 4; ++nt) {
                int h = nt * 16 + lm;
                float v = acc[nt][r] + tp_s[h];
                v = fmaxf(v, 0.f);
                sum = fmaf(v, ov_s[h], sum);
            }
            part[r] = sum;
        }
        #pragma unroll
        for (int off = 1; off < 16; off <<= 1) {
            #pragma unroll
            for (int r = 0; r < 4; ++r)
                part[r] += __shfl_xor(part[r], off);
        }
        if (lm == 0) {
            #pragma unroll
            for (int r = 0; r < 4; ++r)
                alpha_s[row0 + q * 4 + r] = part[r];
        }
    }
    __syncthreads();

    // ---- block softmax over s = 0..199 ----
    float a = (t < S_) ? alpha_s[t] - mk * MASK_SCALE : -INFINITY;
    float m = a;
    #pragma unroll
    for (int off = 1; off < 64; off <<= 1) m = fmaxf(m, __shfl_xor(m, off));
    if (lane == 0) red8[wv] = m;
    __syncthreads();
    m = fmaxf(fmaxf(red8[0], red8[1]), fmaxf(red8[2], red8[3]));
    float e = (t < S_) ? __expf(a - m) : 0.f;
    float ssum = e;
    #pragma unroll
    for (int off = 1; off < 64; off <<= 1) ssum += __shfl_xor(ssum, off);
    if (lane == 0) red8[4 + wv] = ssum;
    __syncthreads();
    float inv = 1.f / (red8[4] + red8[5] + red8[6] + red8[7]);
    __syncthreads();                 // alpha_s reads done before overwrite below
    if (t < S_) alpha_s[t] = e * inv;
    __syncthreads();

    // ---- pooling: out[b][d] = sum_s w[s] * his_bf[s][d] ----
    const int d8 = t & 31;           // 8B index: covers d = d8*4 .. d8*4+3
    const int sg = t >> 5;           // 0..7 s-groups
    float acc0 = 0.f, acc1 = 0.f, acc2 = 0.f, acc3 = 0.f;
    #pragma unroll 5
    for (int s = sg; s < S_; s += 8) {
        float w = alpha_s[s];        // half-wave-uniform broadcast
        int pc = (d8 >> 1) ^ (s & 15);
        ushort4_t v = *(const ushort4_t*)((const char*)hisb + s * 256 + pc * 16 + (d8 & 1) * 8);
        acc0 = fmaf(w, bf2f(v[0]), acc0);
        acc1 = fmaf(w, bf2f(v[1]), acc1);
        acc2 = fmaf(w, bf2f(v[2]), acc2);
        acc3 = fmaf(w, bf2f(v[3]), acc3);
    }
    // combine the two s-groups within each wave
    acc0 += __shfl_xor(acc0, 32);
    acc1 += __shfl_xor(acc1, 32);
    acc2 += __shfl_xor(acc2, 32);
    acc3 += __shfl_xor(acc3, 32);
    if (wv && lane < 32) {
        float4 p; p.x = acc0; p.y = acc1; p.z = acc2; p.w = acc3;
        *(float4*)(&pool_s[(wv - 1) * D_ + d8 * 4]) = p;
    }
    __syncthreads();
    if (wv == 0 && lane < 32) {
        #pragma unroll
        for (int k = 0; k < 3; ++k) {
            const float4 p = *(const float4*)(&pool_s[k * D_ + d8 * 4]);
            acc0 += p.x; acc1 += p.y; acc2 += p.z; acc3 += p.w;
        }
        float4 o; o.x = acc0; o.y = acc1; o.z = acc2; o.w = acc3;
        *(float4*)(out + (size_t)b * D_ + d8 * 4) = o;
    }
}

// ---------------------------------------------------------------------------
extern "C" void kernel_launch(void* const* d_in, const int* in_sizes, int n_in,
                              void* d_out, int out_size, void* d_ws, size_t ws_size,
                              hipStream_t stream) {
    const float* his    = (const float*)d_in[0];
    const float* target = (const float*)d_in[1];
    const float* mask   = (const float*)d_in[2];
    const float* W      = (const float*)d_in[3];
    const float* W_bias = (const float*)d_in[4];
    const float* Ovec   = (const float*)d_in[5];
    // O_bias (d_in[6]) is softmax-invariant -> unused
    float* out = (float*)d_out;

    char* ws = (char*)d_ws;
    unsigned short* wfrag = (unsigned short*)ws;           // 16 KB
    float* tproj          = (float*)(ws + 16384);          // 512 KB

    prep<<<544, 256, 0, stream>>>(W, W_bias, target, wfrag, tproj);
    fused_kernel<<<B_, 256, 0, stream>>>(his, mask, wfrag, tproj, Ovec, out);
}